// Round 1
// 871.622 us; speedup vs baseline: 1.0995x; 1.0995x over previous
//
#include <hip/hip_runtime.h>

constexpr int NX  = 10000;   // X
constexpr int NX4 = NX / 4;  // 2500 float4 per row
constexpr int NY  = 4096;    // Y
constexpr int NY4 = NY / 4;  // 1024 float4 per w_y2z row
constexpr int NZ  = 100;     // Z
constexpr int NT  = 256;

// workspace layout (doubles)
constexpr int WS_XSS  = 0;        // sum(x^2)
constexpr int WS_DSUM = 1;        // sum of new_diff row idx (atomic)
constexpr int WS_LR   = 2;        // learning rate
constexpr int WS_AGEI = 3;        // old age of idx (double)
constexpr int WS_IDX  = 4;        // idx as double
constexpr int WS_PRE  = 8;        // pre[NY]
constexpr int WS_ZNRM = 8 + NY;   // w_y2z row norms [NZ]

using f4 = __attribute__((ext_vector_type(4))) float;

__device__ __forceinline__ double block_reduce(double v, double* sred) {
#pragma unroll
    for (int off = 32; off > 0; off >>= 1)
        v += __shfl_down(v, off, 64);
    int wid  = threadIdx.x >> 6;
    int lane = threadIdx.x & 63;
    __syncthreads();
    if (lane == 0) sred[wid] = v;
    __syncthreads();
    return sred[0] + sred[1] + sred[2] + sred[3];
}

// K1: one block per row y. Streams w/f/d once (float4): copies -> out,
// reductions -> pre/mean, factor output (copy if age<=20, nsf if age>20),
// normalized w_z2y row -> out3. Also computes ||x||^2 locally (k0 folded in);
// block 0 publishes it + zeroes the dsum accumulator for k4/k5.
__global__ __launch_bounds__(NT) void k1(
    const float* __restrict__ x, const int* __restrict__ z,
    const float* __restrict__ w_x2y, const float* __restrict__ w_z2y,
    const float* __restrict__ diff, const float* __restrict__ factor,
    const int* __restrict__ y_age,
    float* __restrict__ out_w, float* __restrict__ out_wz,
    float* __restrict__ out_d, float* __restrict__ out_f,
    double* __restrict__ dws)
{
    __shared__ double sred[4];
    __shared__ double sbr[1];
    const int t = threadIdx.x;
    const int y = blockIdx.x;
    const size_t rb4 = (size_t)y * NX4;     // row base, in float4 units (16B aligned)
    const f4* wr = (const f4*)w_x2y + rb4;
    const f4* fr = (const f4*)factor + rb4;
    const f4* dr = (const f4*)diff + rb4;
    const f4* xr = (const f4*)x;
    f4* o1 = (f4*)out_w + rb4;
    f4* o5 = (f4*)out_d + rb4;
    f4* o6 = (f4*)out_f + rb4;

    const int age = y_age[y];
    const bool young = ((double)age <= 20.0);   // factor passthrough

    double dot = 0.0, sq = 0.0, dsum = 0.0, xss = 0.0;
    for (int i = t; i < NX4; i += NT) {
        f4 wv = __builtin_nontemporal_load(wr + i);
        f4 fv = __builtin_nontemporal_load(fr + i);
        f4 dv = dr[i];                       // keep cached: re-read in pass 2
        f4 xv = xr[i];                       // L2-hot, shared across all blocks
#pragma unroll
        for (int cc = 0; cc < 4; ++cc) {
            double wf = (double)wv[cc] * (double)fv[cc];
            dot  += (double)xv[cc] * wf;
            sq   += wf * wf;
            dsum += (double)dv[cc];
            xss  += (double)xv[cc] * (double)xv[cc];
        }
        __builtin_nontemporal_store(wv, o1 + i);
        __builtin_nontemporal_store(dv, o5 + i);
        if (young) __builtin_nontemporal_store(fv, o6 + i);
    }
    double dotT = block_reduce(dot,  sred);
    double sqT  = block_reduce(sq,   sred);
    double dsT  = block_reduce(dsum, sred);
    double xssT = block_reduce(xss,  sred);

    // w_z2y row: normalize + grab column c
    const int c = z[0];
    double zv = 0.0; float myz = 0.0f;
    if (t < NZ) { myz = w_z2y[(size_t)y * NZ + t]; zv = (double)myz * (double)myz; }
    double zsq = block_reduce(zv, sred);
    double zn = sqrt(zsq); if (zn < 1e-12) zn = 1e-12;
    if (t < NZ) {
        out_wz[(size_t)y * NZ + t] = (float)((double)myz / zn);
        if (t == c) sbr[0] = (double)myz / zn;
    }
    __syncthreads();

    if (t == 0) {
        double xn = sqrt(xssT); if (xn < 1e-12) xn = 1e-12;
        double wn = sqrt(sqT);  if (wn < 1e-12) wn = 1e-12;
        double ybu = dotT / (xn * wn);
        dws[WS_PRE + y] = 0.5 * ybu + 0.5 * sbr[0];
        if (y == 0) { dws[WS_XSS] = xssT; dws[WS_DSUM] = 0.0; }  // for k4/k5 (stream-ordered)
    }

    if (!young) {
        double mean  = dsT / (double)NX;
        double lower = 0.8 * mean, upper = 1.2 * mean;
        double den = lower - upper; if (den < 1e-12) den = 1e-12;
        for (int i = t; i < NX4; i += NT) {
            f4 dv = dr[i];                   // L2-hot re-read
            f4 nsf;
#pragma unroll
            for (int cc = 0; cc < 4; ++cc) {
                double d = (double)dv[cc];
                nsf[cc] = (float)((d < lower) ? 1.0
                         : ((d > upper) ? 0.0 : (d - upper) / den));
            }
            __builtin_nontemporal_store(nsf, o6 + i);
        }
    }
}

// K2: normalize w_y2z rows (float4), store norms
__global__ __launch_bounds__(NT) void k2(
    const float* __restrict__ w_y2z, float* __restrict__ out_yz, double* __restrict__ dws)
{
    __shared__ double sred[4];
    const int zr = blockIdx.x, t = threadIdx.x;
    const f4* r = (const f4*)w_y2z + (size_t)zr * NY4;
    f4* o = (f4*)out_yz + (size_t)zr * NY4;
    double sq = 0.0;
    for (int i = t; i < NY4; i += NT) {
        f4 v = r[i];
#pragma unroll
        for (int cc = 0; cc < 4; ++cc) sq += (double)v[cc] * (double)v[cc];
    }
    sq = block_reduce(sq, sred);
    double n = sqrt(sq); if (n < 1e-12) n = 1e-12;
    for (int i = t; i < NY4; i += NT) {
        f4 v = r[i]; f4 ov;
#pragma unroll
        for (int cc = 0; cc < 4; ++cc) ov[cc] = (float)((double)v[cc] / n);
        o[i] = ov;
    }
    if (t == 0) dws[WS_ZNRM + zr] = n;
}

// K3: competition + all small outputs + row fixups for out3 (idx) / out4 (c)
__global__ __launch_bounds__(NT) void k3(
    const int* __restrict__ z, const float* __restrict__ w_z2y,
    const float* __restrict__ w_y2z, const int* __restrict__ y_age,
    const float* __restrict__ y_thresh, const int* __restrict__ z_age,
    float* __restrict__ out_act, float* __restrict__ out_wz,
    float* __restrict__ out_yz, float* __restrict__ out_yage,
    float* __restrict__ out_zage, float* __restrict__ out_th,
    double* __restrict__ dws)
{
    __shared__ double sval[NT];
    __shared__ int    sidx[NT];
    __shared__ int    scnt[NT];
    __shared__ double sh[8];
    __shared__ double sred[4];
    const int t = threadIdx.x;
    const int c = z[0];

    // argmax(pre), first occurrence
    double bv = -1e300; int bi = 0;
    for (int yy = t; yy < NY; yy += NT) {
        double v = dws[WS_PRE + yy];
        if (v > bv) { bv = v; bi = yy; }
    }
    sval[t] = bv; sidx[t] = bi;
    __syncthreads();
    for (int s = NT / 2; s > 0; s >>= 1) {
        if (t < s) {
            double ov = sval[t + s]; int oi = sidx[t + s];
            if (ov > sval[t] || (ov == sval[t] && oi < sidx[t])) { sval[t] = ov; sidx[t] = oi; }
        }
        __syncthreads();
    }
    if (t == 0) { sh[0] = sval[0]; sh[1] = (double)sidx[0]; }
    __syncthreads();
    const int idx0 = (int)sh[1];
    const double max_resp = sh[0];

    // argmax(pre * unact), count unactivated
    double bv2 = -1e300; int bi2 = 0; int un_cnt = 0;
    for (int yy = t; yy < NY; yy += NT) {
        int un = (y_age[yy] < 1) ? 1 : 0;
        un_cnt += un;
        double v = dws[WS_PRE + yy] * (double)un;
        if (v > bv2) { bv2 = v; bi2 = yy; }
    }
    sval[t] = bv2; sidx[t] = bi2; scnt[t] = un_cnt;
    __syncthreads();
    for (int s = NT / 2; s > 0; s >>= 1) {
        if (t < s) {
            double ov = sval[t + s]; int oi = sidx[t + s];
            if (ov > sval[t] || (ov == sval[t] && oi < sidx[t])) { sval[t] = ov; sidx[t] = oi; }
            scnt[t] += scnt[t + s];
        }
        __syncthreads();
    }
    if (t == 0) {
        int alt = sidx[0];
        bool has_un = (scnt[0] > 0);
        bool keep = (max_resp > (double)y_thresh[idx0]) || (y_age[idx0] < 1);
        int idx = (keep || !has_un) ? idx0 : alt;
        double agei = (double)y_age[idx];
        double lr = 1.0 / (agei + 1.0);
        double lrz = 1.0 / ((double)z_age[c] + 1.0);
        dws[WS_LR] = lr; dws[WS_AGEI] = agei; dws[WS_IDX] = (double)idx;
        sh[2] = (double)idx; sh[3] = lr; sh[4] = lrz; sh[5] = lr * max_resp;
    }
    __syncthreads();
    const int idx = (int)sh[2];
    const double lr = sh[3], lrz = sh[4];

    // ages, thresh, activated count
    int actcnt = 0;
    for (int yy = t; yy < NY; yy += NT) {
        int age = y_age[yy];
        int na = age + ((yy == idx) ? 1 : 0);
        out_yage[yy] = (float)na;
        actcnt += (na >= 1) ? 1 : 0;
        float th = y_thresh[yy];
        out_th[yy] = (yy == idx) ? (float)(sh[5] + (1.0 - lr) * (double)th) : th;
    }
    scnt[t] = actcnt;
    __syncthreads();
    for (int s = NT / 2; s > 0; s >>= 1) {
        if (t < s) scnt[t] += scnt[t + s];
        __syncthreads();
    }
    if (t == 0) out_act[0] = (float)scnt[0];

    if (t < NZ) out_zage[t] = (float)(z_age[t] + ((t == c) ? 1 : 0));

    // out3 row idx: renormalize + lerp toward one-hot(c)
    double zv = 0.0; float myz = 0.0f;
    if (t < NZ) { myz = w_z2y[(size_t)idx * NZ + t]; zv = (double)myz * (double)myz; }
    double zsq = block_reduce(zv, sred);
    double zn = sqrt(zsq); if (zn < 1e-12) zn = 1e-12;
    if (t < NZ) {
        double wn = (double)myz / zn;
        out_wz[(size_t)idx * NZ + t] =
            (float)((1.0 - lr) * wn + lr * ((t == c) ? 1.0 : 0.0));
    }

    // out4 row c: lerp normalized row toward one-hot(idx)  (float4)
    double nc = dws[WS_ZNRM + c];
    const f4* wy = (const f4*)w_y2z + (size_t)c * NY4;
    f4* oy = (f4*)out_yz + (size_t)c * NY4;
    for (int i = t; i < NY4; i += NT) {
        f4 wv = wy[i]; f4 ov;
#pragma unroll
        for (int cc = 0; cc < 4; ++cc) {
            int yy = 4 * i + cc;
            double w = (double)wv[cc] / nc;
            ov[cc] = (float)((1.0 - lrz) * w + lrz * ((yy == idx) ? 1.0 : 0.0));
        }
        oy[i] = ov;
    }
}

// K4: hebbian row idx for w_x2y / diff + sum(new_diff row)  (float4)
__global__ __launch_bounds__(NT) void k4(
    const float* __restrict__ x, const float* __restrict__ w_x2y,
    const float* __restrict__ diff,
    float* __restrict__ out_w, float* __restrict__ out_d,
    double* __restrict__ dws)
{
    __shared__ double sred[4];
    const int idx = (int)dws[WS_IDX];
    const double lr = dws[WS_LR];
    double nx = sqrt(dws[WS_XSS]); if (nx < 1e-12) nx = 1e-12;
    const int i = blockIdx.x * NT + threadIdx.x;
    const size_t rb4 = (size_t)idx * NX4;
    double nds = 0.0;
    if (i < NX4) {
        f4 wv = ((const f4*)w_x2y + rb4)[i];
        f4 dv = ((const f4*)diff + rb4)[i];
        f4 xv = ((const f4*)x)[i];
        f4 ow, od;
#pragma unroll
        for (int cc = 0; cc < 4; ++cc) {
            double nw = (1.0 - lr) * (double)wv[cc] + lr * ((double)xv[cc] / nx);
            double d0 = (double)dv[cc];
            double nd = (1.0 - lr) * d0 + lr * fabs(nw - d0);
            ow[cc] = (float)nw;
            od[cc] = (float)nd;
            nds += nd;
        }
        ((f4*)out_w + rb4)[i] = ow;
        ((f4*)out_d + rb4)[i] = od;
    }
    double s = block_reduce(nds, sred);
    if (threadIdx.x == 0) atomicAdd(&dws[WS_DSUM], s);
}

// K5: factor row idx when age>20 (recompute new_diff in fp64, float4)
__global__ __launch_bounds__(NT) void k5(
    const float* __restrict__ x, const float* __restrict__ w_x2y,
    const float* __restrict__ diff, float* __restrict__ out_f,
    double* __restrict__ dws)
{
    if (dws[WS_AGEI] <= 20.0) return;
    const int idx = (int)dws[WS_IDX];
    const double lr = dws[WS_LR];
    double nx = sqrt(dws[WS_XSS]); if (nx < 1e-12) nx = 1e-12;
    double mean = dws[WS_DSUM] / (double)NX;
    double lower = 0.8 * mean, upper = 1.2 * mean;
    double den = lower - upper; if (den < 1e-12) den = 1e-12;
    const int i = blockIdx.x * NT + threadIdx.x;
    if (i >= NX4) return;
    const size_t rb4 = (size_t)idx * NX4;
    f4 wv = ((const f4*)w_x2y + rb4)[i];
    f4 dv = ((const f4*)diff + rb4)[i];
    f4 xv = ((const f4*)x)[i];
    f4 of;
#pragma unroll
    for (int cc = 0; cc < 4; ++cc) {
        double nw = (1.0 - lr) * (double)wv[cc] + lr * ((double)xv[cc] / nx);
        double d0 = (double)dv[cc];
        double nd = (1.0 - lr) * d0 + lr * fabs(nw - d0);
        of[cc] = (float)((nd < lower) ? 1.0 : ((nd > upper) ? 0.0 : (nd - upper) / den));
    }
    ((f4*)out_f + rb4)[i] = of;
}

extern "C" void kernel_launch(void* const* d_in, const int* in_sizes, int n_in,
                              void* d_out, int out_size, void* d_ws, size_t ws_size,
                              hipStream_t stream) {
    const float* x        = (const float*)d_in[0];
    const int*   z        = (const int*)  d_in[1];
    const float* w_x2y    = (const float*)d_in[2];
    const float* w_z2y    = (const float*)d_in[3];
    const float* w_y2z    = (const float*)d_in[4];
    const float* diff     = (const float*)d_in[5];
    const float* factor   = (const float*)d_in[6];
    const int*   y_age    = (const int*)  d_in[7];
    const float* y_thresh = (const float*)d_in[8];
    const int*   z_age    = (const int*)  d_in[9];

    float* out = (float*)d_out;
    float* o1 = out;                                   // new_w_x2y  [NY*NX]
    float* o2 = o1 + (size_t)NY * NX;                  // y_activated_num [1]
    float* o3 = o2 + 1;                                // new_w_z2y  [NY*NZ]
    float* o4 = o3 + (size_t)NY * NZ;                  // new_w_y2z  [NZ*NY]
    float* o5 = o4 + (size_t)NZ * NY;                  // new_diff   [NY*NX]
    float* o6 = o5 + (size_t)NY * NX;                  // new_factor [NY*NX]
    float* o7 = o6 + (size_t)NY * NX;                  // new_y_age  [NY]
    float* o8 = o7 + NY;                               // new_z_age  [NZ]
    float* o9 = o8 + NZ;                               // new_thresh [NY]

    double* dws = (double*)d_ws;

    k1<<<NY, NT, 0, stream>>>(x, z, w_x2y, w_z2y, diff, factor, y_age,
                              o1, o3, o5, o6, dws);
    k2<<<NZ, NT, 0, stream>>>(w_y2z, o4, dws);
    k3<<<1, NT, 0, stream>>>(z, w_z2y, w_y2z, y_age, y_thresh, z_age,
                             o2, o3, o4, o7, o8, o9, dws);
    k4<<<(NX4 + NT - 1) / NT, NT, 0, stream>>>(x, w_x2y, diff, o1, o5, dws);
    k5<<<(NX4 + NT - 1) / NT, NT, 0, stream>>>(x, w_x2y, diff, o6, dws);
}

// Round 2
// 855.221 us; speedup vs baseline: 1.1205x; 1.0192x over previous
//
#include <hip/hip_runtime.h>

constexpr int NX  = 10000;   // X
constexpr int NX4 = NX / 4;  // 2500 float4 per row
constexpr int NY  = 4096;    // Y
constexpr int NY4 = NY / 4;  // 1024 float4 per w_y2z row
constexpr int NZ  = 100;     // Z
constexpr int NT  = 256;
constexpr int KITER = (NX4 + NT - 1) / NT;   // 10 (last trip partial: t < 196)

// workspace layout (doubles)
constexpr int WS_XSS  = 0;        // sum(x^2)
constexpr int WS_DSUM = 1;        // sum of new_diff row idx (atomic)
constexpr int WS_LR   = 2;        // learning rate
constexpr int WS_AGEI = 3;        // old age of idx (double)
constexpr int WS_IDX  = 4;        // idx as double
constexpr int WS_PRE  = 8;        // pre[NY]
constexpr int WS_ZNRM = 8 + NY;   // w_y2z row norms [NZ]

using f4 = __attribute__((ext_vector_type(4))) float;

__device__ __forceinline__ double block_reduce(double v, double* sred) {
#pragma unroll
    for (int off = 32; off > 0; off >>= 1)
        v += __shfl_down(v, off, 64);
    int wid  = threadIdx.x >> 6;
    int lane = threadIdx.x & 63;
    __syncthreads();
    if (lane == 0) sred[wid] = v;
    __syncthreads();
    return sred[0] + sred[1] + sred[2] + sred[3];
}

// K1: one block per row y. Streams w/f/d once (float4, fully unrolled, diff row
// pinned in registers): copies -> out, reductions -> pre/mean, factor output
// (copy if age<=20, nsf-from-registers if age>20), normalized w_z2y row -> out3.
// ||x||^2 computed locally; block 0 publishes it + zeroes dsum for k4/k5.
__global__ __launch_bounds__(NT, 4) void k1(
    const float* __restrict__ x, const int* __restrict__ z,
    const float* __restrict__ w_x2y, const float* __restrict__ w_z2y,
    const float* __restrict__ diff, const float* __restrict__ factor,
    const int* __restrict__ y_age,
    float* __restrict__ out_w, float* __restrict__ out_wz,
    float* __restrict__ out_d, float* __restrict__ out_f,
    double* __restrict__ dws)
{
    __shared__ double sred[4];
    __shared__ double sbr[1];
    const int t = threadIdx.x;
    const int y = blockIdx.x;
    const size_t rb4 = (size_t)y * NX4;     // row base, in float4 units (16B aligned)
    const f4* wr = (const f4*)w_x2y + rb4;
    const f4* fr = (const f4*)factor + rb4;
    const f4* dr = (const f4*)diff + rb4;
    const f4* xr = (const f4*)x;
    f4* o1 = (f4*)out_w + rb4;
    f4* o5 = (f4*)out_d + rb4;
    f4* o6 = (f4*)out_f + rb4;

    const int age = y_age[y];
    const bool young = ((double)age <= 20.0);   // factor passthrough

    // hoist the small w_z2y row load so it's in flight under the streaming loop
    const int c = z[0];
    float myz = 0.0f;
    if (t < NZ) myz = w_z2y[(size_t)y * NZ + t];

    f4 dv[KITER];                               // diff row, register-resident
    double dot = 0.0, sq = 0.0, dsum = 0.0, xss = 0.0;
#pragma unroll
    for (int k = 0; k < KITER; ++k) {
        const int i = t + k * NT;
        if (i < NX4) {
            f4 wv = __builtin_nontemporal_load(wr + i);
            f4 fv = __builtin_nontemporal_load(fr + i);
            f4 d  = __builtin_nontemporal_load(dr + i);
            f4 xv = xr[i];                       // L2-hot, shared across blocks
            dv[k] = d;
#pragma unroll
            for (int cc = 0; cc < 4; ++cc) {
                double wf = (double)wv[cc] * (double)fv[cc];
                dot  += (double)xv[cc] * wf;
                sq   += wf * wf;
                dsum += (double)d[cc];
                xss  += (double)xv[cc] * (double)xv[cc];
            }
            __builtin_nontemporal_store(wv, o1 + i);
            __builtin_nontemporal_store(d,  o5 + i);
            if (young) __builtin_nontemporal_store(fv, o6 + i);
        }
    }
    double dotT = block_reduce(dot,  sred);
    double sqT  = block_reduce(sq,   sred);
    double dsT  = block_reduce(dsum, sred);
    double xssT = block_reduce(xss,  sred);

    // w_z2y row: normalize + grab column c
    double zv = (t < NZ) ? (double)myz * (double)myz : 0.0;
    double zsq = block_reduce(zv, sred);
    double zn = sqrt(zsq); if (zn < 1e-12) zn = 1e-12;
    if (t < NZ) {
        out_wz[(size_t)y * NZ + t] = (float)((double)myz / zn);
        if (t == c) sbr[0] = (double)myz / zn;
    }
    __syncthreads();

    if (t == 0) {
        double xn = sqrt(xssT); if (xn < 1e-12) xn = 1e-12;
        double wn = sqrt(sqT);  if (wn < 1e-12) wn = 1e-12;
        double ybu = dotT / (xn * wn);
        dws[WS_PRE + y] = 0.5 * ybu + 0.5 * sbr[0];
        if (y == 0) { dws[WS_XSS] = xssT; dws[WS_DSUM] = 0.0; }  // for k4/k5 (stream-ordered)
    }

    if (!young) {
        double mean  = dsT / (double)NX;
        double lower = 0.8 * mean, upper = 1.2 * mean;
        double den = lower - upper; if (den < 1e-12) den = 1e-12;
#pragma unroll
        for (int k = 0; k < KITER; ++k) {
            const int i = t + k * NT;
            if (i < NX4) {
                f4 d = dv[k];                    // register-resident, no re-read
                f4 nsf;
#pragma unroll
                for (int cc = 0; cc < 4; ++cc) {
                    double dd = (double)d[cc];
                    nsf[cc] = (float)((dd < lower) ? 1.0
                             : ((dd > upper) ? 0.0 : (dd - upper) / den));
                }
                __builtin_nontemporal_store(nsf, o6 + i);
            }
        }
    }
}

// K2: normalize w_y2z rows (float4), store norms
__global__ __launch_bounds__(NT) void k2(
    const float* __restrict__ w_y2z, float* __restrict__ out_yz, double* __restrict__ dws)
{
    __shared__ double sred[4];
    const int zr = blockIdx.x, t = threadIdx.x;
    const f4* r = (const f4*)w_y2z + (size_t)zr * NY4;
    f4* o = (f4*)out_yz + (size_t)zr * NY4;
    double sq = 0.0;
    for (int i = t; i < NY4; i += NT) {
        f4 v = r[i];
#pragma unroll
        for (int cc = 0; cc < 4; ++cc) sq += (double)v[cc] * (double)v[cc];
    }
    sq = block_reduce(sq, sred);
    double n = sqrt(sq); if (n < 1e-12) n = 1e-12;
    for (int i = t; i < NY4; i += NT) {
        f4 v = r[i]; f4 ov;
#pragma unroll
        for (int cc = 0; cc < 4; ++cc) ov[cc] = (float)((double)v[cc] / n);
        o[i] = ov;
    }
    if (t == 0) dws[WS_ZNRM + zr] = n;
}

// K3: competition + all small outputs + row fixups for out3 (idx) / out4 (c)
__global__ __launch_bounds__(NT) void k3(
    const int* __restrict__ z, const float* __restrict__ w_z2y,
    const float* __restrict__ w_y2z, const int* __restrict__ y_age,
    const float* __restrict__ y_thresh, const int* __restrict__ z_age,
    float* __restrict__ out_act, float* __restrict__ out_wz,
    float* __restrict__ out_yz, float* __restrict__ out_yage,
    float* __restrict__ out_zage, float* __restrict__ out_th,
    double* __restrict__ dws)
{
    __shared__ double sval[NT];
    __shared__ int    sidx[NT];
    __shared__ int    scnt[NT];
    __shared__ double sh[8];
    __shared__ double sred[4];
    const int t = threadIdx.x;
    const int c = z[0];

    // argmax(pre), first occurrence
    double bv = -1e300; int bi = 0;
    for (int yy = t; yy < NY; yy += NT) {
        double v = dws[WS_PRE + yy];
        if (v > bv) { bv = v; bi = yy; }
    }
    sval[t] = bv; sidx[t] = bi;
    __syncthreads();
    for (int s = NT / 2; s > 0; s >>= 1) {
        if (t < s) {
            double ov = sval[t + s]; int oi = sidx[t + s];
            if (ov > sval[t] || (ov == sval[t] && oi < sidx[t])) { sval[t] = ov; sidx[t] = oi; }
        }
        __syncthreads();
    }
    if (t == 0) { sh[0] = sval[0]; sh[1] = (double)sidx[0]; }
    __syncthreads();
    const int idx0 = (int)sh[1];
    const double max_resp = sh[0];

    // argmax(pre * unact), count unactivated
    double bv2 = -1e300; int bi2 = 0; int un_cnt = 0;
    for (int yy = t; yy < NY; yy += NT) {
        int un = (y_age[yy] < 1) ? 1 : 0;
        un_cnt += un;
        double v = dws[WS_PRE + yy] * (double)un;
        if (v > bv2) { bv2 = v; bi2 = yy; }
    }
    sval[t] = bv2; sidx[t] = bi2; scnt[t] = un_cnt;
    __syncthreads();
    for (int s = NT / 2; s > 0; s >>= 1) {
        if (t < s) {
            double ov = sval[t + s]; int oi = sidx[t + s];
            if (ov > sval[t] || (ov == sval[t] && oi < sidx[t])) { sval[t] = ov; sidx[t] = oi; }
            scnt[t] += scnt[t + s];
        }
        __syncthreads();
    }
    if (t == 0) {
        int alt = sidx[0];
        bool has_un = (scnt[0] > 0);
        bool keep = (max_resp > (double)y_thresh[idx0]) || (y_age[idx0] < 1);
        int idx = (keep || !has_un) ? idx0 : alt;
        double agei = (double)y_age[idx];
        double lr = 1.0 / (agei + 1.0);
        double lrz = 1.0 / ((double)z_age[c] + 1.0);
        dws[WS_LR] = lr; dws[WS_AGEI] = agei; dws[WS_IDX] = (double)idx;
        sh[2] = (double)idx; sh[3] = lr; sh[4] = lrz; sh[5] = lr * max_resp;
    }
    __syncthreads();
    const int idx = (int)sh[2];
    const double lr = sh[3], lrz = sh[4];

    // ages, thresh, activated count
    int actcnt = 0;
    for (int yy = t; yy < NY; yy += NT) {
        int age = y_age[yy];
        int na = age + ((yy == idx) ? 1 : 0);
        out_yage[yy] = (float)na;
        actcnt += (na >= 1) ? 1 : 0;
        float th = y_thresh[yy];
        out_th[yy] = (yy == idx) ? (float)(sh[5] + (1.0 - lr) * (double)th) : th;
    }
    scnt[t] = actcnt;
    __syncthreads();
    for (int s = NT / 2; s > 0; s >>= 1) {
        if (t < s) scnt[t] += scnt[t + s];
        __syncthreads();
    }
    if (t == 0) out_act[0] = (float)scnt[0];

    if (t < NZ) out_zage[t] = (float)(z_age[t] + ((t == c) ? 1 : 0));

    // out3 row idx: renormalize + lerp toward one-hot(c)
    double zv = 0.0; float myz = 0.0f;
    if (t < NZ) { myz = w_z2y[(size_t)idx * NZ + t]; zv = (double)myz * (double)myz; }
    double zsq = block_reduce(zv, sred);
    double zn = sqrt(zsq); if (zn < 1e-12) zn = 1e-12;
    if (t < NZ) {
        double wn = (double)myz / zn;
        out_wz[(size_t)idx * NZ + t] =
            (float)((1.0 - lr) * wn + lr * ((t == c) ? 1.0 : 0.0));
    }

    // out4 row c: lerp normalized row toward one-hot(idx)  (float4)
    double nc = dws[WS_ZNRM + c];
    const f4* wy = (const f4*)w_y2z + (size_t)c * NY4;
    f4* oy = (f4*)out_yz + (size_t)c * NY4;
    for (int i = t; i < NY4; i += NT) {
        f4 wv = wy[i]; f4 ov;
#pragma unroll
        for (int cc = 0; cc < 4; ++cc) {
            int yy = 4 * i + cc;
            double w = (double)wv[cc] / nc;
            ov[cc] = (float)((1.0 - lrz) * w + lrz * ((yy == idx) ? 1.0 : 0.0));
        }
        oy[i] = ov;
    }
}

// K4: hebbian row idx for w_x2y / diff + sum(new_diff row)  (float4)
__global__ __launch_bounds__(NT) void k4(
    const float* __restrict__ x, const float* __restrict__ w_x2y,
    const float* __restrict__ diff,
    float* __restrict__ out_w, float* __restrict__ out_d,
    double* __restrict__ dws)
{
    __shared__ double sred[4];
    const int idx = (int)dws[WS_IDX];
    const double lr = dws[WS_LR];
    double nx = sqrt(dws[WS_XSS]); if (nx < 1e-12) nx = 1e-12;
    const int i = blockIdx.x * NT + threadIdx.x;
    const size_t rb4 = (size_t)idx * NX4;
    double nds = 0.0;
    if (i < NX4) {
        f4 wv = ((const f4*)w_x2y + rb4)[i];
        f4 dv = ((const f4*)diff + rb4)[i];
        f4 xv = ((const f4*)x)[i];
        f4 ow, od;
#pragma unroll
        for (int cc = 0; cc < 4; ++cc) {
            double nw = (1.0 - lr) * (double)wv[cc] + lr * ((double)xv[cc] / nx);
            double d0 = (double)dv[cc];
            double nd = (1.0 - lr) * d0 + lr * fabs(nw - d0);
            ow[cc] = (float)nw;
            od[cc] = (float)nd;
            nds += nd;
        }
        ((f4*)out_w + rb4)[i] = ow;
        ((f4*)out_d + rb4)[i] = od;
    }
    double s = block_reduce(nds, sred);
    if (threadIdx.x == 0) atomicAdd(&dws[WS_DSUM], s);
}

// K5: factor row idx when age>20 (recompute new_diff in fp64, float4)
__global__ __launch_bounds__(NT) void k5(
    const float* __restrict__ x, const float* __restrict__ w_x2y,
    const float* __restrict__ diff, float* __restrict__ out_f,
    double* __restrict__ dws)
{
    if (dws[WS_AGEI] <= 20.0) return;
    const int idx = (int)dws[WS_IDX];
    const double lr = dws[WS_LR];
    double nx = sqrt(dws[WS_XSS]); if (nx < 1e-12) nx = 1e-12;
    double mean = dws[WS_DSUM] / (double)NX;
    double lower = 0.8 * mean, upper = 1.2 * mean;
    double den = lower - upper; if (den < 1e-12) den = 1e-12;
    const int i = blockIdx.x * NT + threadIdx.x;
    if (i >= NX4) return;
    const size_t rb4 = (size_t)idx * NX4;
    f4 wv = ((const f4*)w_x2y + rb4)[i];
    f4 dv = ((const f4*)diff + rb4)[i];
    f4 xv = ((const f4*)x)[i];
    f4 of;
#pragma unroll
    for (int cc = 0; cc < 4; ++cc) {
        double nw = (1.0 - lr) * (double)wv[cc] + lr * ((double)xv[cc] / nx);
        double d0 = (double)dv[cc];
        double nd = (1.0 - lr) * d0 + lr * fabs(nw - d0);
        of[cc] = (float)((nd < lower) ? 1.0 : ((nd > upper) ? 0.0 : (nd - upper) / den));
    }
    ((f4*)out_f + rb4)[i] = of;
}

extern "C" void kernel_launch(void* const* d_in, const int* in_sizes, int n_in,
                              void* d_out, int out_size, void* d_ws, size_t ws_size,
                              hipStream_t stream) {
    const float* x        = (const float*)d_in[0];
    const int*   z        = (const int*)  d_in[1];
    const float* w_x2y    = (const float*)d_in[2];
    const float* w_z2y    = (const float*)d_in[3];
    const float* w_y2z    = (const float*)d_in[4];
    const float* diff     = (const float*)d_in[5];
    const float* factor   = (const float*)d_in[6];
    const int*   y_age    = (const int*)  d_in[7];
    const float* y_thresh = (const float*)d_in[8];
    const int*   z_age    = (const int*)  d_in[9];

    float* out = (float*)d_out;
    float* o1 = out;                                   // new_w_x2y  [NY*NX]
    float* o2 = o1 + (size_t)NY * NX;                  // y_activated_num [1]
    float* o3 = o2 + 1;                                // new_w_z2y  [NY*NZ]
    float* o4 = o3 + (size_t)NY * NZ;                  // new_w_y2z  [NZ*NY]
    float* o5 = o4 + (size_t)NZ * NY;                  // new_diff   [NY*NX]
    float* o6 = o5 + (size_t)NY * NX;                  // new_factor [NY*NX]
    float* o7 = o6 + (size_t)NY * NX;                  // new_y_age  [NY]
    float* o8 = o7 + NY;                               // new_z_age  [NZ]
    float* o9 = o8 + NZ;                               // new_thresh [NY]

    double* dws = (double*)d_ws;

    k1<<<NY, NT, 0, stream>>>(x, z, w_x2y, w_z2y, diff, factor, y_age,
                              o1, o3, o5, o6, dws);
    k2<<<NZ, NT, 0, stream>>>(w_y2z, o4, dws);
    k3<<<1, NT, 0, stream>>>(z, w_z2y, w_y2z, y_age, y_thresh, z_age,
                             o2, o3, o4, o7, o8, o9, dws);
    k4<<<(NX4 + NT - 1) / NT, NT, 0, stream>>>(x, w_x2y, diff, o1, o5, dws);
    k5<<<(NX4 + NT - 1) / NT, NT, 0, stream>>>(x, w_x2y, diff, o6, dws);
}